// Round 9
// baseline (103.138 us; speedup 1.0000x reference)
//
#include <hip/hip_runtime.h>

#define NE     100000
#define NR     64
#define DIM    16
#define NHOP   2
#define NMEM   32
#define NNODES 16384

#define WPITCH 20                 // W staging pitch in floats (80 B)
#define ET_BYTES (NE * DIM * 2)   // 3.2 MB f16 entity table in d_ws
#define NB_ET  ((NE * DIM / 4 + 255) / 256)   // 1563 blocks for et conversion

typedef __attribute__((ext_vector_type(2))) _Float16 half2_t;

static __device__ __forceinline__ half2_t as_h2(unsigned u) {
    union { unsigned i; half2_t h; } c; c.i = u; return c.h;
}
static __device__ __forceinline__ float qdot2(unsigned u, unsigned ip, float q) {
#if __has_builtin(__builtin_amdgcn_fdot2)
    return __builtin_amdgcn_fdot2(as_h2(u), as_h2(ip), q, false);
#else
    half2_t a = as_h2(u), b = as_h2(ip);
    return q + (float)a.x * (float)b.x + (float)a.y * (float)b.y;
#endif
}
static __device__ __forceinline__ float dpp_sum16(float v) {
    union { int i; float f; } a, b;
    a.f = v;
    b.i = __builtin_amdgcn_update_dpp(0, a.i, 0xB1,  0xf, 0xf, true); a.f += b.f; // quad_perm [1,0,3,2]
    b.i = __builtin_amdgcn_update_dpp(0, a.i, 0x4E,  0xf, 0xf, true); a.f += b.f; // quad_perm [2,3,0,1]
    b.i = __builtin_amdgcn_update_dpp(0, a.i, 0x124, 0xf, 0xf, true); a.f += b.f; // row_ror:4
    b.i = __builtin_amdgcn_update_dpp(0, a.i, 0x128, 0xf, 0xf, true); a.f += b.f; // row_ror:8
    return a.f;
}
static __device__ __forceinline__ float bcast(float v, int l) {
    return __int_as_float(__builtin_amdgcn_readlane(__float_as_int(v), l));
}
static __device__ __forceinline__ unsigned short f2h(float f) {
    union { _Float16 h; unsigned short s; } c; c.h = (_Float16)f; return c.s;
}
static __device__ __forceinline__ unsigned pack2h(float a, float b) {
    union { _Float16 h[2]; unsigned u; } c;
    c.h[0] = (_Float16)a; c.h[1] = (_Float16)b;
    return c.u;
}

// ---- Prep: (a) entity_emb fp32 -> f16 table; (b) relation_emb fp32 ->
// f16 TRANSPOSED + XOR-swizzled global table (exact byte layout the main
// kernel copies flat into LDS; swizzle as R2/R7, measured 0 conflicts).
extern "C" __global__ void __launch_bounds__(256)
prep_kernel(const float* __restrict__ ent, const float* __restrict__ rel,
            _Float16* __restrict__ et, unsigned short* __restrict__ rtg, int n4)
{
    const int b = blockIdx.x, tid = threadIdx.x;
    if (b < NB_ET) {
        int i = b * 256 + tid;
        if (i < n4) {
            float4 v = ((const float4*)ent)[i];
            union { _Float16 h[4]; unsigned long long u; } c;
            c.h[0] = (_Float16)v.x; c.h[1] = (_Float16)v.y;
            c.h[2] = (_Float16)v.z; c.h[3] = (_Float16)v.w;
            *(unsigned long long*)(et + 4 * (long long)i) = c.u;
        }
    } else {
        int j = (b - NB_ET) * 256 + tid;          // 0..1023
        const float4* rel4 = (const float4*)rel;
        #pragma unroll
        for (int k = 0; k < 4; ++k) {
            int vidx = k * 1024 + j;              // 4096 float4s total
            float4 v = rel4[vidx];
            int k0 = vidx * 4;
            int r  = k0 >> 8;
            int kk = k0 & 255;
            int d  = kk >> 4;
            int e0 = kk & 15;
            int phys = ((d >> 2) + (e0 >> 2)) & 3;
            unsigned short* p = &rtg[r * 256 + e0 * 16 + phys * 4 + (d & 3)];
            p[0]  = f2h(v.x);
            p[16] = f2h(v.y);
            p[32] = f2h(v.z);
            p[48] = f2h(v.w);
        }
    }
}

// Persistent main kernel: 1024 blocks = 256 CUs x 4 resident (LDS-limited).
// Each block stages the R-table ONCE, then processes 16 nodes (4/wave) with
// no further barriers; node iterations are software-pipelined depth-1.
extern "C" __global__ void __launch_bounds__(256, 4)
ripple_kernel(const int* __restrict__ nodes,
              const int* __restrict__ mh,
              const int* __restrict__ mr,
              const int* __restrict__ mt,
              const _Float16* __restrict__ et,
              const unsigned short* __restrict__ rtg,
              const float* __restrict__ W,
              float* __restrict__ out)
{
    __shared__ __align__(16) unsigned short rt[NR * 256];   // 32768 B
    __shared__ __align__(16) float ws[DIM * WPITCH];        // 1280 B

    const int tid  = threadIdx.x;
    const int lane = tid & 63;
    const int wid  = tid >> 6;
    const int g    = lane >> 4;   // mem-group 0..3 -> owns mems [8g, 8g+8)
    const int e    = lane & 15;   // dim index

    // ---- Stage R-table + W into LDS (once per block) ----
    {
        const float4* src = (const float4*)rtg;
        float4* dst = (float4*)rt;
        #pragma unroll
        for (int i = 0; i < 8; ++i) dst[i * 256 + tid] = src[i * 256 + tid];
        ws[(tid >> 4) * WPITCH + (tid & 15)] = W[tid];
    }
    __syncthreads();

    // Per-lane byte offsets into a relation's row for logical chunk j (swizzled)
    int voff[4];
    {
        const int s = e >> 2;
        #pragma unroll
        for (int j = 0; j < 4; ++j)
            voff[j] = e * 32 + (((j + s) & 3) << 3);
    }

    const int nbase = blockIdx.x * 16 + wid * 4;   // 4 consecutive nodes per wave

    // idx ping-pong buffers: [parity][hop*3 + {h,r,t}] as int4 pairs
    int4 idx[2][12];
    int  nd[2];

    // prologue: node 0's indices
    {
        const int n   = nbase;
        const int ib0 = n * NMEM + g * 8;
        const int ib1 = NNODES * NMEM + ib0;
        const int4* p;
        p = (const int4*)(mh + ib0); idx[0][0] = p[0]; idx[0][1] = p[1];
        p = (const int4*)(mr + ib0); idx[0][2] = p[0]; idx[0][3] = p[1];
        p = (const int4*)(mt + ib0); idx[0][4] = p[0]; idx[0][5] = p[1];
        p = (const int4*)(mh + ib1); idx[0][6] = p[0]; idx[0][7] = p[1];
        p = (const int4*)(mr + ib1); idx[0][8] = p[0]; idx[0][9] = p[1];
        p = (const int4*)(mt + ib1); idx[0][10] = p[0]; idx[0][11] = p[1];
        nd[0] = nodes[n];
    }

    #pragma unroll
    for (int i = 0; i < 4; ++i) {
        const int  cur = i & 1, nxt = cur ^ 1;
        const int  n   = nbase + i;

        // unpack current node's indices
        int hi0[8], ri0[8], ti0[8], hi1[8], ri1[8], ti1[8];
        *(int4*)&hi0[0] = idx[cur][0];  *(int4*)&hi0[4] = idx[cur][1];
        *(int4*)&ri0[0] = idx[cur][2];  *(int4*)&ri0[4] = idx[cur][3];
        *(int4*)&ti0[0] = idx[cur][4];  *(int4*)&ti0[4] = idx[cur][5];
        *(int4*)&hi1[0] = idx[cur][6];  *(int4*)&hi1[4] = idx[cur][7];
        *(int4*)&ri1[0] = idx[cur][8];  *(int4*)&ri1[4] = idx[cur][9];
        *(int4*)&ti1[0] = idx[cur][10]; *(int4*)&ti1[4] = idx[cur][11];

        // burst-issue all entity gathers for this node (both hops)
        float item = (float)et[nd[cur] * DIM + e];
        float hv0[8], tv0[8], hv1[8], tv1[8];
        #pragma unroll
        for (int it = 0; it < 8; ++it) {
            hv0[it] = (float)et[hi0[it] * DIM + e];
            tv0[it] = (float)et[ti0[it] * DIM + e];
            hv1[it] = (float)et[hi1[it] * DIM + e];
            tv1[it] = (float)et[ti1[it] * DIM + e];
        }

        // prefetch next node's indices (independent; hides under compute)
        if (i < 3) {
            const int n2  = n + 1;
            const int jb0 = n2 * NMEM + g * 8;
            const int jb1 = NNODES * NMEM + jb0;
            const int4* p;
            p = (const int4*)(mh + jb0); idx[nxt][0] = p[0]; idx[nxt][1] = p[1];
            p = (const int4*)(mr + jb0); idx[nxt][2] = p[0]; idx[nxt][3] = p[1];
            p = (const int4*)(mt + jb0); idx[nxt][4] = p[0]; idx[nxt][5] = p[1];
            p = (const int4*)(mh + jb1); idx[nxt][6] = p[0]; idx[nxt][7] = p[1];
            p = (const int4*)(mr + jb1); idx[nxt][8] = p[0]; idx[nxt][9] = p[1];
            p = (const int4*)(mt + jb1); idx[nxt][10] = p[0]; idx[nxt][11] = p[1];
            nd[nxt] = nodes[n2];
        }

        // ---- compute both hops ----
        float out_acc = 0.f;
        #pragma unroll
        for (int hop = 0; hop < NHOP; ++hop) {
            const int*   ri = hop ? ri1 : ri0;
            const float* hv = hop ? hv1 : hv0;
            const float* tv = hop ? tv1 : tv0;

            // item vector -> 8 packed f16 pairs, wave-uniform (SGPRs)
            unsigned ip[8];
            #pragma unroll
            for (int j = 0; j < 8; ++j)
                ip[j] = pack2h(bcast(item, 2 * j), bcast(item, 2 * j + 1));

            // online softmax over the 8 owned memories
            float Z = 0.f, o = 0.f;
            #pragma unroll
            for (int it = 0; it < 8; ++it) {
                const char* rbase = (const char*)rt + (ri[it] << 9);
                float q = 0.f;
                #pragma unroll
                for (int j = 0; j < 4; ++j) {
                    uint2 u = *(const uint2*)(rbase + voff[j]);
                    q = qdot2(u.x, ip[2 * j + 0], q);
                    q = qdot2(u.y, ip[2 * j + 1], q);
                }
                float sc = dpp_sum16(q * hv[it]);   // item . (R @ h)
                float ex = __expf(sc);              // scores small: no max pass
                Z += ex;
                o += ex * tv[it];
            }
            Z += __shfl_xor(Z, 16);
            Z += __shfl_xor(Z, 32);
            o += __shfl_xor(o, 16);
            o += __shfl_xor(o, 32);
            o *= 1.f / Z;

            out_acc += (hop == 0) ? 2.f * o : o;    // faithful: o1 + 2*o0

            // item = (item + o) @ W.T ; W row e from LDS
            const float v = item + o;
            float nit = 0.f;
            const float4* wr = (const float4*)&ws[e * WPITCH];
            #pragma unroll
            for (int j = 0; j < 4; ++j) {
                float4 w = wr[j];
                nit += w.x * bcast(v, 4 * j + 0) + w.y * bcast(v, 4 * j + 1)
                     + w.z * bcast(v, 4 * j + 2) + w.w * bcast(v, 4 * j + 3);
            }
            item = nit;
        }

        if (lane < 16) out[n * DIM + e] = out_acc;
    }
}

extern "C" void kernel_launch(void* const* d_in, const int* in_sizes, int n_in,
                              void* d_out, int out_size, void* d_ws, size_t ws_size,
                              hipStream_t stream) {
    const int*   nodes = (const int*)d_in[0];
    const int*   mh    = (const int*)d_in[1];
    const int*   mr    = (const int*)d_in[2];
    const int*   mt    = (const int*)d_in[3];
    const float* ent   = (const float*)d_in[4];
    const float* rel   = (const float*)d_in[5];
    const float* W     = (const float*)d_in[6];
    float*       out   = (float*)d_out;

    _Float16*       et  = (_Float16*)d_ws;                           // 3.2 MB
    unsigned short* rtg = (unsigned short*)((char*)d_ws + ET_BYTES); // 32 KB

    const int n4 = NE * DIM / 4;              // 400000 float4s
    prep_kernel<<<NB_ET + 4, 256, 0, stream>>>(ent, rel, et, rtg, n4);

    dim3 grid(NNODES / 16);  // 1024 persistent blocks: 4/CU, 16 nodes each
    dim3 block(256);
    ripple_kernel<<<grid, block, 0, stream>>>(nodes, mh, mr, mt, et, rtg, W, out);
}

// Round 10
// 100.486 us; speedup vs baseline: 1.0264x; 1.0264x over previous
//
#include <hip/hip_runtime.h>

#define NE     100000
#define NR     64
#define DIM    16
#define NHOP   2
#define NMEM   32
#define NNODES 16384

#define WPITCH 20                 // W staging pitch in floats (80 B)
#define ET_BYTES (NE * DIM * 2)   // 3.2 MB f16 entity table in d_ws
#define NB_ET  ((NE * DIM / 4 + 255) / 256)   // 1563 blocks for et conversion

typedef __attribute__((ext_vector_type(2))) _Float16 half2_t;

static __device__ __forceinline__ half2_t as_h2(unsigned u) {
    union { unsigned i; half2_t h; } c; c.i = u; return c.h;
}
static __device__ __forceinline__ float qdot2(unsigned u, unsigned ip, float q) {
#if __has_builtin(__builtin_amdgcn_fdot2)
    return __builtin_amdgcn_fdot2(as_h2(u), as_h2(ip), q, false);
#else
    half2_t a = as_h2(u), b = as_h2(ip);
    return q + (float)a.x * (float)b.x + (float)a.y * (float)b.y;
#endif
}
// Sum across 16 contiguous lanes, broadcast. Pure DPP (VALU pipe) — the ONLY
// cross-lane reduction left in the kernel; stays inside a 16-lane row.
static __device__ __forceinline__ float dpp_sum16(float v) {
    union { int i; float f; } a, b;
    a.f = v;
    b.i = __builtin_amdgcn_update_dpp(0, a.i, 0xB1,  0xf, 0xf, true); a.f += b.f; // quad_perm [1,0,3,2]
    b.i = __builtin_amdgcn_update_dpp(0, a.i, 0x4E,  0xf, 0xf, true); a.f += b.f; // quad_perm [2,3,0,1]
    b.i = __builtin_amdgcn_update_dpp(0, a.i, 0x124, 0xf, 0xf, true); a.f += b.f; // row_ror:4
    b.i = __builtin_amdgcn_update_dpp(0, a.i, 0x128, 0xf, 0xf, true); a.f += b.f; // row_ror:8
    return a.f;
}
static __device__ __forceinline__ unsigned short f2h(float f) {
    union { _Float16 h; unsigned short s; } c; c.h = (_Float16)f; return c.s;
}
static __device__ __forceinline__ unsigned pack2h(float a, float b) {
    union { _Float16 h[2]; unsigned u; } c;
    c.h[0] = (_Float16)a; c.h[1] = (_Float16)b;
    return c.u;
}

// ---- Prep: (a) entity_emb fp32 -> f16 table; (b) relation_emb fp32 ->
// f16 TRANSPOSED + XOR-swizzled global table (byte layout the main kernel
// copies flat into LDS; swizzle as R2/R7, measured 0 conflicts).
extern "C" __global__ void __launch_bounds__(256)
prep_kernel(const float* __restrict__ ent, const float* __restrict__ rel,
            _Float16* __restrict__ et, unsigned short* __restrict__ rtg, int n4)
{
    const int b = blockIdx.x, tid = threadIdx.x;
    if (b < NB_ET) {
        int i = b * 256 + tid;
        if (i < n4) {
            float4 v = ((const float4*)ent)[i];
            union { _Float16 h[4]; unsigned long long u; } c;
            c.h[0] = (_Float16)v.x; c.h[1] = (_Float16)v.y;
            c.h[2] = (_Float16)v.z; c.h[3] = (_Float16)v.w;
            *(unsigned long long*)(et + 4 * (long long)i) = c.u;
        }
    } else {
        int j = (b - NB_ET) * 256 + tid;          // 0..1023
        const float4* rel4 = (const float4*)rel;
        #pragma unroll
        for (int k = 0; k < 4; ++k) {
            int vidx = k * 1024 + j;              // 4096 float4s total
            float4 v = rel4[vidx];
            int k0 = vidx * 4;
            int r  = k0 >> 8;
            int kk = k0 & 255;
            int d  = kk >> 4;
            int e0 = kk & 15;
            int phys = ((d >> 2) + (e0 >> 2)) & 3;
            unsigned short* p = &rtg[r * 256 + e0 * 16 + phys * 4 + (d & 3)];
            p[0]  = f2h(v.x);
            p[16] = f2h(v.y);
            p[32] = f2h(v.z);
            p[48] = f2h(v.w);
        }
    }
}

// Main kernel: 1024 blocks (exactly 4/CU, one generation). One 16-lane group
// owns one full node (all 32 memories, both hops): zero cross-group shuffles;
// all reductions are 16-lane DPP; item/W broadcasts via tiny wave-private LDS.
extern "C" __global__ void __launch_bounds__(256, 4)
ripple_kernel(const int* __restrict__ nodes,
              const int* __restrict__ mh,
              const int* __restrict__ mr,
              const int* __restrict__ mt,
              const _Float16* __restrict__ et,
              const unsigned short* __restrict__ rtg,
              const float* __restrict__ W,
              float* __restrict__ out)
{
    __shared__ __align__(16) unsigned short rt[NR * 256];   // 32768 B
    __shared__ __align__(16) float ws[DIM * WPITCH];        // 1280 B
    __shared__ __align__(16) float sc32[4][4][16];          // 1024 B wave-private scratch

    const int tid  = threadIdx.x;
    const int lane = tid & 63;
    const int wid  = tid >> 6;
    const int g    = lane >> 4;   // group 0..3 -> owns node nbase+g
    const int e    = lane & 15;   // dim index

    // ---- Stage R-table + W into LDS (once per block, flat copy) ----
    {
        const float4* src = (const float4*)rtg;
        float4* dst = (float4*)rt;
        #pragma unroll
        for (int i = 0; i < 8; ++i) dst[i * 256 + tid] = src[i * 256 + tid];
        ws[(tid >> 4) * WPITCH + (tid & 15)] = W[tid];
    }
    __syncthreads();

    // Per-lane byte offsets into a relation's row for logical chunk j (swizzled)
    int voff[4];
    {
        const int s = e >> 2;
        #pragma unroll
        for (int j = 0; j < 4; ++j)
            voff[j] = e * 32 + (((j + s) & 3) << 3);
    }

    const int n  = blockIdx.x * 16 + wid * 4 + g;   // this group's node
    const int nd = nodes[n];
    float item    = (float)et[nd * DIM + e];
    float out_acc = 0.f;

    const float4* sp = (const float4*)&sc32[wid][g][0];

    #pragma unroll
    for (int hop = 0; hop < NHOP; ++hop) {
        const int ibase = hop * (NNODES * NMEM) + n * NMEM;

        // broadcast item within the group -> 8 packed f16 pairs (per-group!)
        sc32[wid][g][e] = item;
        float4 f0 = sp[0], f1 = sp[1], f2 = sp[2], f3 = sp[3];
        unsigned ip[8];
        ip[0] = pack2h(f0.x, f0.y); ip[1] = pack2h(f0.z, f0.w);
        ip[2] = pack2h(f1.x, f1.y); ip[3] = pack2h(f1.z, f1.w);
        ip[4] = pack2h(f2.x, f2.y); ip[5] = pack2h(f2.z, f2.w);
        ip[6] = pack2h(f3.x, f3.y); ip[7] = pack2h(f3.z, f3.w);

        float Z = 0.f, o = 0.f;

        // 4 batches of 8 memories; all 32 handled by THIS group
        #pragma unroll
        for (int k = 0; k < 4; ++k) {
            const int mb = ibase + 8 * k;
            int hi[8], ri[8], ti[8];
            {   // group-uniform int4 loads (same addr across the 16 lanes)
                const int4* p;
                p = (const int4*)(mh + mb); *(int4*)&hi[0] = p[0]; *(int4*)&hi[4] = p[1];
                p = (const int4*)(mr + mb); *(int4*)&ri[0] = p[0]; *(int4*)&ri[4] = p[1];
                p = (const int4*)(mt + mb); *(int4*)&ti[0] = p[0]; *(int4*)&ti[4] = p[1];
            }
            // burst-issue this batch's 16 gathers
            float hv[8], tv[8];
            #pragma unroll
            for (int j = 0; j < 8; ++j) {
                hv[j] = (float)et[hi[j] * DIM + e];
                tv[j] = (float)et[ti[j] * DIM + e];
            }
            // compute the 8 memory scores (all reductions 16-lane DPP)
            #pragma unroll
            for (int j = 0; j < 8; ++j) {
                const char* rbase = (const char*)rt + (ri[j] << 9);
                float q = 0.f;
                #pragma unroll
                for (int c = 0; c < 4; ++c) {
                    uint2 u = *(const uint2*)(rbase + voff[c]);
                    q = qdot2(u.x, ip[2 * c + 0], q);
                    q = qdot2(u.y, ip[2 * c + 1], q);
                }
                float sc = dpp_sum16(q * hv[j]);   // item . (R @ h), group-uniform
                float ex = __expf(sc);             // scores small: no max pass
                Z += ex;                            // group-uniform
                o += ex * tv[j];                    // per-lane e
            }
        }
        o *= 1.f / Z;                               // softmax-weighted tails

        if (hop == 0) {
            out_acc = 2.f * o;                      // faithful: o1 + 2*o0
            // item = (item + o) @ W.T ; broadcast v within group via scratch
            const float v = item + o;
            sc32[wid][g][e] = v;
            float4 v0 = sp[0], v1 = sp[1], v2 = sp[2], v3 = sp[3];
            const float4* wr = (const float4*)&ws[e * WPITCH];
            float4 w0 = wr[0], w1 = wr[1], w2 = wr[2], w3 = wr[3];
            item = w0.x * v0.x + w0.y * v0.y + w0.z * v0.z + w0.w * v0.w
                 + w1.x * v1.x + w1.y * v1.y + w1.z * v1.z + w1.w * v1.w
                 + w2.x * v2.x + w2.y * v2.y + w2.z * v2.z + w2.w * v2.w
                 + w3.x * v3.x + w3.y * v3.y + w3.z * v3.z + w3.w * v3.w;
        } else {
            out_acc += o;                           // hop-1 W-update is dead code
        }
    }

    out[n * DIM + e] = out_acc;                     // all 64 lanes store
}

extern "C" void kernel_launch(void* const* d_in, const int* in_sizes, int n_in,
                              void* d_out, int out_size, void* d_ws, size_t ws_size,
                              hipStream_t stream) {
    const int*   nodes = (const int*)d_in[0];
    const int*   mh    = (const int*)d_in[1];
    const int*   mr    = (const int*)d_in[2];
    const int*   mt    = (const int*)d_in[3];
    const float* ent   = (const float*)d_in[4];
    const float* rel   = (const float*)d_in[5];
    const float* W     = (const float*)d_in[6];
    float*       out   = (float*)d_out;

    _Float16*       et  = (_Float16*)d_ws;                           // 3.2 MB
    unsigned short* rtg = (unsigned short*)((char*)d_ws + ET_BYTES); // 32 KB

    const int n4 = NE * DIM / 4;              // 400000 float4s
    prep_kernel<<<NB_ET + 4, 256, 0, stream>>>(ent, rel, et, rtg, n4);

    dim3 grid(NNODES / 16);  // 1024 blocks = 4/CU, 16 nodes each (4/wave, 1/group)
    dim3 block(256);
    ripple_kernel<<<grid, block, 0, stream>>>(nodes, mh, mr, mt, et, rtg, W, out);
}